// Round 8
// baseline (228.850 us; speedup 1.0000x reference)
//
#include <hip/hip_runtime.h>

typedef __bf16 bf16x8 __attribute__((ext_vector_type(8)));
typedef float f32x4 __attribute__((ext_vector_type(4)));
typedef unsigned int uint4v __attribute__((ext_vector_type(4)));
typedef unsigned short ushort_t;
typedef unsigned int uint_t;

#define RS 0.08838834764831845f   // 1/sqrt(128)

__device__ __forceinline__ ushort_t f2bf(float f) {
    uint_t u = __float_as_uint(f);
    u += 0x7FFFu + ((u >> 16) & 1u);   // round-to-nearest-even
    return (ushort_t)(u >> 16);
}
__device__ __forceinline__ uint_t pack2(float a, float b) {
    return (uint_t)f2bf(a) | ((uint_t)f2bf(b) << 16);
}
union U4B8 { uint4v u; bf16x8 b; };
__device__ __forceinline__ bf16x8 as_bf(uint4v u) { U4B8 x; x.u = u; return x.b; }

// padded xs frag addressing: frag stride 1072B (67x16), phase stride 272B (17x16)
__device__ __forceinline__ int xfrag(int f, int lane) {
    return f * 1072 + ((lane >> 4) * 272) + ((lane & 15) * 16);
}

// ---------------------------------------------------------------------------
// R17 = R16 fusion with the three diagnosed defects fixed:
//  (1) P1 K' bank conflicts (6.1M): lane->(m = w*8+lane>>3, dd = lane&7,
//      cols dd*4+32j). wqL f32x4 reads: banks dd*4 (8 quads) + broadcast
//      across m-groups -> conflict-free, 128B unique/instr. keysL XOR-swizzled
//      at stage (e ^= (m&7)<<2) -> kv scalar reads spread over 8 banks.
//  (2) loop drain-0 (R10 redux): distance-2 counted vmcnt. GA/GB register
//      ping-pong (static names). Bottom of pair k: vmcnt(8) [loads(k+1)
//      landed; loads(k+2) stay IN FLIGHT], pack+ds_write, issue loads(k+3),
//      lgkmcnt(0), RAW s_barrier (no vmcnt drain in loop).
//  (3) everything else = proven R2 compute structure.
// LDS map (147712B):
//   [0,98304)      ring 3x32KB  | P0/P1 alias: wqL f32[128][128] @0,
//                                 keysL f32[64][128] (XOR-swz) @65536
//   [32768,67072)  xs A-frag staging (dead before packWrite(0)/(1))
//   [98304,114688) kp ushort[8192]; [114688,147456) attn f32[64][128] XOR-swz
//   [147456,147712) cb f32[64]
// Aliasing proof: wqL/keysL dead after P1 barrier; xs written P2 (after P1),
// dead after A-frag loads (before packWrite(0)); buf b written at bottom of
// pair b-1 mod..., last read 2 barriers earlier.
// ---------------------------------------------------------------------------
__global__ __launch_bounds__(512, 2) void fused_kernel(
    const float* __restrict__ x, const float* __restrict__ keys,
    const float* __restrict__ ops, const float* __restrict__ Wq,
    const float* __restrict__ bq, float* __restrict__ out)
{
    __shared__ __align__(16) unsigned char lds[147712];
    uint4v* bb = (uint4v*)lds;                    // ring 3 x 2048 uint4v
    float* wqL = (float*)lds;                     // [0,65536)
    float* keysL = (float*)(lds + 65536);         // [65536,98304), XOR-swz
    unsigned char* xs = lds + 32768;              // [32768,67072)
    ushort_t* kpL = (ushort_t*)(lds + 98304);
    float* attn_f = (float*)(lds + 114688);
    float* cbL = (float*)(lds + 147456);

    const int tid = threadIdx.x;          // 0..511
    const int lane = tid & 63;
    const int w = tid >> 6;               // wave 0..7
    const int q = lane >> 4;
    const int l15 = lane & 15;
    const int tb = blockIdx.x >> 1;       // token tile 0..127
    const int dh = blockIdx.x & 1;
    const int t0 = tb * 128;
    const int dtp = w & 3;                // d-16-tile within half
    const int tg = w >> 2;                // token 64-group

    // ---- P0: stage Wq (64KB) + keys (32KB, XOR-swizzled) f32 -> LDS
    {
        float4* wd = (float4*)wqL;
        const float4* wq4 = (const float4*)Wq;
        #pragma unroll
        for (int i = 0; i < 8; ++i) wd[i * 512 + tid] = wq4[i * 512 + tid];
        const float4* ks4 = (const float4*)keys;
        float4* kd = (float4*)keysL;
        #pragma unroll
        for (int i = 0; i < 4; ++i) {
            int g = i * 512 + tid;                 // chunk id 0..2047
            int m = g >> 5, ec = g & 31;
            kd[(m << 5) | (ec ^ (m & 7))] = ks4[g];
        }
    }
    __syncthreads();

    // ---- P1: K'[m][d] = sum_e keys[m][e]*Wq[e][d] (exact f32 VALU) + cb
    {
        const int m = w * 8 + (lane >> 3);     // wave covers 8 slots
        const int dd = lane & 7;               // cols d = dd*4 + 32*jj
        const int sm = (m & 7) << 2;
        f32x4 acc0 = {}, acc1 = {}, acc2 = {}, acc3 = {};
        const f32x4* wrow = (const f32x4*)(wqL + dd * 4);
        #pragma unroll 4
        for (int e = 0; e < 128; ++e) {
            float kv = keysL[m * 128 + (e ^ sm)];
            const f32x4* wr = wrow + e * 32;   // e*128 floats
            f32x4 w0 = wr[0], w1 = wr[8], w2 = wr[16], w3 = wr[24];
            #pragma unroll
            for (int r = 0; r < 4; ++r) {
                acc0[r] = fmaf(kv, w0[r], acc0[r]);
                acc1[r] = fmaf(kv, w1[r], acc1[r]);
                acc2[r] = fmaf(kv, w2[r], acc2[r]);
                acc3[r] = fmaf(kv, w3[r], acc3[r]);
            }
        }
        // kp frag pack: d -> ki=jj, qq=dd>>1, j=(dd&1)*4+r
        const int mh = m >> 4, ml = m & 15, qq = dd >> 1, jh = (dd & 1) * 4;
        f32x4 av[4] = { acc0, acc1, acc2, acc3 };
        #pragma unroll
        for (int jj = 0; jj < 4; ++jj) {
            int base = (((jj * 4 + mh) * 64) + (qq * 16 + ml)) * 8 + jh;
            *(uint_t*)(kpL + base)     = pack2(av[jj][0], av[jj][1]);
            *(uint_t*)(kpL + base + 2) = pack2(av[jj][2], av[jj][3]);
        }
        if (tid < 64) {                        // cb[m] = keys[m].bq
            const f32x4* kr = (const f32x4*)keysL + tid * 32;
            const f32x4* bq4 = (const f32x4*)bq;
            float s = 0.f;
            #pragma unroll 8
            for (int ec = 0; ec < 32; ++ec) {
                f32x4 kk = kr[ec ^ (tid & 7)];
                f32x4 bv = bq4[ec];
                s = fmaf(kk[0], bv[0], s); s = fmaf(kk[1], bv[1], s);
                s = fmaf(kk[2], bv[2], s); s = fmaf(kk[3], bv[3], s);
            }
            cbL[tid] = s;
        }
    }
    __syncthreads();   // wqL/keysL dead; kp + cb published

    // ---- reg staging: pair p = slots (2p,2p+1); thread's 4 frags f=w*4+j
    int bofs[4], wofs[4];
    #pragma unroll
    for (int j = 0; j < 4; ++j) {
        const int f = w * 4 + j;
        const int sl = f >> 4, ks = (f >> 2) & 3, dtl = f & 3;
        bofs[j] = sl * 16384 + (dh * 64 + dtl * 16 + l15) * 128 + ks * 32 + (q << 3);
        wofs[j] = sl * 1024 + ks * 256 + dtl * 64 + lane;
    }
    float4 GA[8], GB[8];
    auto issueLoads = [&](int p, float4 (&G)[8]) {
        const float* base = ops + (size_t)p * 32768;
        #pragma unroll
        for (int j = 0; j < 4; ++j) {
            G[j * 2]     = *(const float4*)(base + bofs[j]);
            G[j * 2 + 1] = *(const float4*)(base + bofs[j] + 4);
        }
    };
    auto packWrite = [&](float4 (&G)[8], int b) {
        #pragma unroll
        for (int j = 0; j < 4; ++j) {
            float4 v0 = G[j * 2], v1 = G[j * 2 + 1];
            uint4v o = { pack2(v0.x, v0.y), pack2(v0.z, v0.w),
                         pack2(v1.x, v1.y), pack2(v1.z, v1.w) };
            bb[b * 2048 + wofs[j]] = o;
        }
    };

    issueLoads(0, GA);   // latency hides under P2+P3

    // ---- P2: x tile (128x128) -> bf16 A-frag order (xs)
    {
        const float4* x4 = (const float4*)(x + (size_t)t0 * 128);
        #pragma unroll
        for (int it = 0; it < 4; ++it) {
            int i = it * 512 + tid;
            int t = i >> 4, kc = i & 15;
            float4 a = x4[t * 32 + kc * 2];
            float4 b2 = x4[t * 32 + kc * 2 + 1];
            uint4v o = { pack2(a.x, a.y), pack2(a.z, a.w),
                         pack2(b2.x, b2.y), pack2(b2.z, b2.w) };
            *(uint4v*)(xs + ((t >> 4) * 4 + (kc >> 2)) * 1072
                          + (kc & 3) * 272 + (t & 15) * 16) = o;
        }
    }
    __syncthreads();

    // ---- P3: attention (wave w owns tokens w*16..w*16+15), all 64 slots
    {
        f32x4 L0 = {0,0,0,0}, L1 = {0,0,0,0}, L2 = {0,0,0,0}, L3 = {0,0,0,0};
        const uint4v* kpf = (const uint4v*)kpL;
        #pragma unroll
        for (int ki = 0; ki < 4; ++ki) {
            bf16x8 a = *(const bf16x8*)(xs + xfrag(w * 4 + ki, lane));
            L0 = __builtin_amdgcn_mfma_f32_16x16x32_bf16(a, as_bf(kpf[(ki*4+0)*64 + lane]), L0, 0,0,0);
            L1 = __builtin_amdgcn_mfma_f32_16x16x32_bf16(a, as_bf(kpf[(ki*4+1)*64 + lane]), L1, 0,0,0);
            L2 = __builtin_amdgcn_mfma_f32_16x16x32_bf16(a, as_bf(kpf[(ki*4+2)*64 + lane]), L2, 0,0,0);
            L3 = __builtin_amdgcn_mfma_f32_16x16x32_bf16(a, as_bf(kpf[(ki*4+3)*64 + lane]), L3, 0,0,0);
        }
        float c0 = cbL[l15], c1 = cbL[16 + l15], c2 = cbL[32 + l15], c3 = cbL[48 + l15];
        #pragma unroll
        for (int r = 0; r < 4; ++r) {
            float v0 = (L0[r] + c0) * RS;
            float v1 = (L1[r] + c1) * RS;
            float v2 = (L2[r] + c2) * RS;
            float v3 = (L3[r] + c3) * RS;
            float mx = fmaxf(fmaxf(v0, v1), fmaxf(v2, v3));
            #pragma unroll
            for (int off = 1; off < 16; off <<= 1) mx = fmaxf(mx, __shfl_xor(mx, off));
            float e0 = __expf(v0 - mx), e1 = __expf(v1 - mx),
                  e2 = __expf(v2 - mx), e3 = __expf(v3 - mx);
            float sm = e0 + e1 + e2 + e3;
            #pragma unroll
            for (int off = 1; off < 16; off <<= 1) sm += __shfl_xor(sm, off);
            float inv = 1.0f / sm;
            int t = w * 16 + q * 4 + r;
            int ts = t ^ ((l15 & 7) << 2);   // XOR bank-swizzle
            attn_f[(     l15) * 128 + ts] = e0 * inv;
            attn_f[(16 + l15) * 128 + ts] = e1 * inv;
            attn_f[(32 + l15) * 128 + ts] = e2 * inv;
            attn_f[(48 + l15) * 128 + ts] = e3 * inv;
        }
    }

    // ---- A-frags for this wave's 64-token group
    bf16x8 A[4][4];
    #pragma unroll
    for (int tf = 0; tf < 4; ++tf)
        #pragma unroll
        for (int ki = 0; ki < 4; ++ki)
            A[tf][ki] = *(const bf16x8*)(xs + xfrag(tg * 16 + tf * 4 + ki, lane));

    __syncthreads();   // xs dead everywhere; attn published; vmcnt drained

    f32x4 C[4] = {};
    auto computePair = [&](int p) {
        const uint4v* bbuf = bb + (p % 3) * 2048 + dtp * 64 + lane;
        #pragma unroll
        for (int sl = 0; sl < 2; ++sl) {
            const int m = p * 2 + sl;
            const int msw = (m & 7) << 2;
            f32x4 S[4] = {};
            __builtin_amdgcn_s_setprio(1);
            #pragma unroll
            for (int ki = 0; ki < 4; ++ki) {
                bf16x8 bfrag = as_bf(bbuf[sl * 1024 + ki * 256]);
                #pragma unroll
                for (int tf = 0; tf < 4; ++tf)
                    S[tf] = __builtin_amdgcn_mfma_f32_16x16x32_bf16(A[tf][ki], bfrag, S[tf], 0,0,0);
            }
            __builtin_amdgcn_s_setprio(0);
            #pragma unroll
            for (int tf = 0; tf < 4; ++tf) {
                int ta = (tg * 64 + tf * 16 + q * 4) ^ msw;
                f32x4 af = *(const f32x4*)&attn_f[m * 128 + ta];
                #pragma unroll
                for (int r = 0; r < 4; ++r)
                    C[tf][r] = fmaf(af[r], S[tf][r], C[tf][r]);
            }
        }
    };

    // ---- prime: GA(loads 0) -> buf0; issue loads 1->GB, 2->GA
    packWrite(GA, 0);
    issueLoads(1, GB);
    issueLoads(2, GA);
    asm volatile("s_waitcnt lgkmcnt(0)" ::: "memory");
    __builtin_amdgcn_s_barrier();

    // ---- main loop: pairs 0..29 (2-unrolled for static GA/GB), peel 30,31.
    // Bottom of pair k: vmcnt(8) -> loads(k+1) landed, loads(k+2) in flight
    // ACROSS the barrier (never drain to 0 in the loop).
    #pragma unroll 1
    for (int p = 0; p < 30; p += 2) {
        computePair(p);
        asm volatile("s_waitcnt vmcnt(8)" ::: "memory");
        packWrite(GB, (p + 1) % 3);
        issueLoads(p + 3, GB);
        asm volatile("s_waitcnt lgkmcnt(0)" ::: "memory");
        __builtin_amdgcn_s_barrier();

        computePair(p + 1);
        asm volatile("s_waitcnt vmcnt(8)" ::: "memory");
        packWrite(GA, (p + 2) % 3);
        if (p + 4 < 32) issueLoads(p + 4, GA);
        asm volatile("s_waitcnt lgkmcnt(0)" ::: "memory");
        __builtin_amdgcn_s_barrier();
    }
    computePair(30);
    asm volatile("s_waitcnt vmcnt(0)" ::: "memory");
    packWrite(GB, 31 % 3);
    asm volatile("s_waitcnt lgkmcnt(0)" ::: "memory");
    __builtin_amdgcn_s_barrier();
    computePair(31);

    // ---- Epilogue: direct stores (complete sums; no atomics)
    float* op = out + (size_t)t0 * 128 + dh * 64 + dtp * 16 + l15;
    #pragma unroll
    for (int tf = 0; tf < 4; ++tf)
        #pragma unroll
        for (int r = 0; r < 4; ++r)
            op[(size_t)(tf * 16 + q * 4 + r + tg * 64) * 128] = C[tf][r];
}

// ---------------------------------------------------------------------------
extern "C" void kernel_launch(void* const* d_in, const int* in_sizes, int n_in,
                              void* d_out, int out_size, void* d_ws, size_t ws_size,
                              hipStream_t stream)
{
    const float* x    = (const float*)d_in[0];   // (4,4096,128)
    const float* keys = (const float*)d_in[1];   // (64,128)
    const float* ops  = (const float*)d_in[2];   // (64,128,128)
    const float* Wq   = (const float*)d_in[3];   // (128,128)
    const float* bq   = (const float*)d_in[4];   // (128,)
    float* out = (float*)d_out;

    (void)d_ws; (void)ws_size;   // single self-sufficient dispatch
    fused_kernel<<<256, 512, 0, stream>>>(x, keys, ops, Wq, bq, out);
}

// Round 9
// 178.515 us; speedup vs baseline: 1.2820x; 1.2820x over previous
//
#include <hip/hip_runtime.h>

typedef __bf16 bf16x8 __attribute__((ext_vector_type(8)));
typedef float f32x4 __attribute__((ext_vector_type(4)));
typedef unsigned int uint4v __attribute__((ext_vector_type(4)));
typedef unsigned short ushort_t;
typedef unsigned int uint_t;

#define RS 0.08838834764831845f   // 1/sqrt(128)

__device__ __forceinline__ ushort_t f2bf(float f) {
    uint_t u = __float_as_uint(f);
    u += 0x7FFFu + ((u >> 16) & 1u);   // round-to-nearest-even
    return (ushort_t)(u >> 16);
}
__device__ __forceinline__ uint_t pack2(float a, float b) {
    return (uint_t)f2bf(a) | ((uint_t)f2bf(b) << 16);
}
union U4B8 { uint4v u; bf16x8 b; };
__device__ __forceinline__ bf16x8 as_bf(uint4v u) { U4B8 x; x.u = u; return x.b; }

// padded xs frag addressing: frag stride 1072B (67x16), phase stride 272B (17x16)
__device__ __forceinline__ int xfrag(int f, int lane) {
    return f * 1072 + ((lane >> 4) * 272) + ((lane & 15) * 16);
}

// ---------------------------------------------------------------------------
// Prep (one dispatch, 576 blocks) — R11-proven, verbatim. Blocks 0..63:
// K'[m]=keys[m]@Wq + cb[m]=bq.keys[m]. Blocks 64..575: swizzle ops -> bf16
// B-frag order: h = m*2048 + (dt>>2)*1024 + ks*256 + (dt&3)*64 + L
// ---------------------------------------------------------------------------
__global__ __launch_bounds__(256) void prep_kernel(
    const float* __restrict__ ops, const float* __restrict__ keys,
    const float* __restrict__ Wq, const float* __restrict__ bq,
    uint4v* __restrict__ ops_sw, ushort_t* __restrict__ kp_sw,
    float* __restrict__ cb)
{
    const int tid = threadIdx.x;
    const int b = blockIdx.x;
    if (b >= 64) {
        int g = (b - 64) * 256 + tid;     // [0, 131072)
        int L = g & 63, dt = (g >> 6) & 7, ks = (g >> 9) & 3, m = g >> 11;
        int d = dt * 16 + (L & 15);
        int e0 = ks * 32 + ((L >> 4) << 3);
        const float4* s = (const float4*)(ops + (((size_t)(m * 128 + d)) << 7) + e0);
        float4 v0 = s[0], v1 = s[1];
        uint4v o = { pack2(v0.x, v0.y), pack2(v0.z, v0.w),
                     pack2(v1.x, v1.y), pack2(v1.z, v1.w) };
        int h = m * 2048 + (dt >> 2) * 1024 + ks * 256 + (dt & 3) * 64 + L;
        ops_sw[h] = o;
    } else {
        __shared__ float red[256];
        const int m = b;
        const int d = tid & 127, eh = tid >> 7;
        const float* kr = keys + m * 128 + eh * 64;
        const float* wc = Wq + (size_t)(eh * 64) * 128 + d;
        float acc = 0.f;
        #pragma unroll 8
        for (int e = 0; e < 64; ++e)
            acc = fmaf(kr[e], wc[(size_t)e * 128], acc);
        red[tid] = acc;
        __syncthreads();
        if (tid < 128) {
            float v = red[tid] + red[tid + 128];
            int ki = d >> 5, qq = (d >> 3) & 3, j = d & 7;
            kp_sw[((((ki * 4 + (m >> 4)) * 64) + (qq * 16 + (m & 15))) << 3) | j] = f2bf(v);
        } else if (tid >= 192) {
            int lane = tid - 192;
            float p = keys[m * 128 + lane] * bq[lane]
                    + keys[m * 128 + 64 + lane] * bq[64 + lane];
            #pragma unroll
            for (int off = 1; off < 64; off <<= 1) p += __shfl_xor(p, off);
            if (lane == 0) cb[m] = p;
        }
    }
}

// ---------------------------------------------------------------------------
// Main: 256 blocks (1/CU), 512 threads (8 waves). Block = 128t x 64d x all
// 64 slots; wave = (slh=w&1 slot parity, dtp=w>>1 d-16-tile) — R14's map
// (verified correct), which makes every wave's B-frags PRIVATE to that wave.
// R18: NO LDS B-ring, NO loop barriers, NO staging, NO inline asm. Each wave
// streams its 4KB/pair B-slice DIRECTLY global(L2-resident ops_sw, 2MB) ->
// registers with distance-2 prefetch (B0/B1 static ping-pong, R9's proven
// codegen pattern: compiler emits its own counted vmcnt before first use).
// Per-pair/CU budget: MFMA 1240cy (critical) >> L2 585cy >> LDS ~1KB (attn
// broadcasts only). Waves drift freely for all 32 pairs; 2 waves/SIMD
// mutually fill stalls (m114). Prefetch slack = one full pair (~1240cy)
// >> L2 latency (~300cy).
// LDS (67072B): [0,32768) attn f32[64][128] XOR-swz; [32768,67072) xs;
// epilogue parity-reduction buffer reuses [0,32768) after a barrier.
// ---------------------------------------------------------------------------
__global__ __launch_bounds__(512, 2) void main_kernel(
    const float* __restrict__ x, const float* __restrict__ cb,
    const ushort_t* __restrict__ kp_sw, const uint4v* __restrict__ ops_sw,
    float* __restrict__ out)
{
    __shared__ __align__(16) unsigned char lds[67072];
    float* attn_f = (float*)lds;                  // [m][t ^ ((m&7)<<2)]
    unsigned char* xs = lds + 32768;              // A-frag staging

    const int tid = threadIdx.x;          // 0..511
    const int lane = tid & 63;
    const int w = tid >> 6;               // wave 0..7
    const int q = lane >> 4;
    const int l15 = lane & 15;
    const int tb = blockIdx.x >> 1;       // token tile 0..127
    const int dh = blockIdx.x & 1;
    const int t0 = tb * 128;
    const int slh = w & 1;                // slot parity
    const int dtp = w >> 1;               // d-16-tile within half

    // ---- Phase 1: stage x tile (128x128) -> bf16 A-frag order (xs, padded)
    {
        const float4* x4 = (const float4*)(x + (size_t)t0 * 128);
        #pragma unroll
        for (int it = 0; it < 4; ++it) {
            int i = it * 512 + tid;
            int t = i >> 4, kc = i & 15;
            float4 a = x4[t * 32 + kc * 2];
            float4 b2 = x4[t * 32 + kc * 2 + 1];
            uint4v o = { pack2(a.x, a.y), pack2(a.z, a.w),
                         pack2(b2.x, b2.y), pack2(b2.z, b2.w) };
            *(uint4v*)(xs + ((t >> 4) * 4 + (kc >> 2)) * 1072
                          + (kc & 3) * 272 + (t & 15) * 16) = o;
        }
    }
    __syncthreads();

    // ---- Phase 2: attention (wave w owns tokens w*16..w*16+15), all 64 slots
    {
        f32x4 L0 = {0,0,0,0}, L1 = {0,0,0,0}, L2 = {0,0,0,0}, L3 = {0,0,0,0};
        const uint4v* kpf = (const uint4v*)kp_sw;
        #pragma unroll
        for (int ki = 0; ki < 4; ++ki) {
            bf16x8 a = *(const bf16x8*)(xs + xfrag(w * 4 + ki, lane));
            L0 = __builtin_amdgcn_mfma_f32_16x16x32_bf16(a, as_bf(kpf[(ki*4+0)*64 + lane]), L0, 0,0,0);
            L1 = __builtin_amdgcn_mfma_f32_16x16x32_bf16(a, as_bf(kpf[(ki*4+1)*64 + lane]), L1, 0,0,0);
            L2 = __builtin_amdgcn_mfma_f32_16x16x32_bf16(a, as_bf(kpf[(ki*4+2)*64 + lane]), L2, 0,0,0);
            L3 = __builtin_amdgcn_mfma_f32_16x16x32_bf16(a, as_bf(kpf[(ki*4+3)*64 + lane]), L3, 0,0,0);
        }
        float c0 = cb[l15], c1 = cb[16 + l15], c2 = cb[32 + l15], c3 = cb[48 + l15];
        #pragma unroll
        for (int r = 0; r < 4; ++r) {
            float v0 = (L0[r] + c0) * RS;
            float v1 = (L1[r] + c1) * RS;
            float v2 = (L2[r] + c2) * RS;
            float v3 = (L3[r] + c3) * RS;
            float mx = fmaxf(fmaxf(v0, v1), fmaxf(v2, v3));
            #pragma unroll
            for (int off = 1; off < 16; off <<= 1) mx = fmaxf(mx, __shfl_xor(mx, off));
            float e0 = __expf(v0 - mx), e1 = __expf(v1 - mx),
                  e2 = __expf(v2 - mx), e3 = __expf(v3 - mx);
            float sm = e0 + e1 + e2 + e3;
            #pragma unroll
            for (int off = 1; off < 16; off <<= 1) sm += __shfl_xor(sm, off);
            float inv = 1.0f / sm;
            int t = w * 16 + q * 4 + r;
            int ts = t ^ ((l15 & 7) << 2);   // XOR bank-swizzle (bits 2..4)
            attn_f[(     l15) * 128 + ts] = e0 * inv;
            attn_f[(16 + l15) * 128 + ts] = e1 * inv;
            attn_f[(32 + l15) * 128 + ts] = e2 * inv;
            attn_f[(48 + l15) * 128 + ts] = e3 * inv;
        }
    }

    // ---- A-frags for ALL 8 token-16-groups (wave MFMAs every token)
    bf16x8 A[8][4];
    #pragma unroll
    for (int tf = 0; tf < 8; ++tf)
        #pragma unroll
        for (int ki = 0; ki < 4; ++ki)
            A[tf][ki] = *(const bf16x8*)(xs + xfrag(tf * 4 + ki, lane));

    __syncthreads();   // attn published; last barrier before epilogue

    // ---- Phase 3: 32 pairs, barrier-free direct global->reg B stream.
    // My B-slice for pair p: ops_sw[(2p+slh)*2048 + dh*1024 + dtp*64 + lane
    //                               + ks*256],  ks = 0..3  (4 x 16B loads)
    const uint4v* myB = ops_sw + (size_t)slh * 2048 + dh * 1024 + dtp * 64 + lane;

    uint4v B0[4], B1[4];
    auto issue = [&](int p, uint4v (&B)[4]) {
        const uint4v* src = myB + (size_t)p * 4096;
        #pragma unroll
        for (int ks = 0; ks < 4; ++ks) B[ks] = src[ks * 256];
    };

    f32x4 C[8] = {};   // partial sums over this wave's slot parity

    auto computePair = [&](int p, uint4v (&Bv)[4]) {
        const int m = 2 * p + slh;
        const int msw = (m & 7) << 2;
        bf16x8 Bf[4];
        #pragma unroll
        for (int ki = 0; ki < 4; ++ki) Bf[ki] = as_bf(Bv[ki]);
        #pragma unroll
        for (int th = 0; th < 2; ++th) {
            f32x4 S[4] = {};
            __builtin_amdgcn_s_setprio(1);
            #pragma unroll
            for (int ki = 0; ki < 4; ++ki)
                #pragma unroll
                for (int tf = 0; tf < 4; ++tf)
                    S[tf] = __builtin_amdgcn_mfma_f32_16x16x32_bf16(
                        A[th * 4 + tf][ki], Bf[ki], S[tf], 0, 0, 0);
            __builtin_amdgcn_s_setprio(0);
            #pragma unroll
            for (int tf = 0; tf < 4; ++tf) {
                int ta = ((th * 4 + tf) * 16 + q * 4) ^ msw;
                f32x4 af = *(const f32x4*)&attn_f[m * 128 + ta];
                #pragma unroll
                for (int r = 0; r < 4; ++r)
                    C[th * 4 + tf][r] = fmaf(af[r], S[tf][r], C[th * 4 + tf][r]);
            }
        }
    };

    issue(0, B0);
    issue(1, B1);
    #pragma unroll 1
    for (int p = 0; p < 30; p += 2) {
        computePair(p, B0);          // compiler inserts counted vmcnt for B0
        issue(p + 2, B0);            // refill after last read of B0
        computePair(p + 1, B1);
        issue(p + 3, B1);
    }
    computePair(30, B0);
    computePair(31, B1);

    // ---- Epilogue: cross-parity reduction (attn buffer dead -> reuse),
    // then direct stores by even-parity waves.
    __syncthreads();
    f32x4* rb = (f32x4*)lds;   // 4 dtp x 8 tf x 64 lanes = 32 KB
    if (slh == 1) {
        #pragma unroll
        for (int tf = 0; tf < 8; ++tf)
            rb[dtp * 512 + tf * 64 + lane] = C[tf];
    }
    __syncthreads();
    if (slh == 0) {
        float* op = out + (size_t)t0 * 128 + dh * 64 + dtp * 16 + l15;
        #pragma unroll
        for (int tf = 0; tf < 8; ++tf) {
            f32x4 other = rb[dtp * 512 + tf * 64 + lane];
            #pragma unroll
            for (int r = 0; r < 4; ++r)
                op[(size_t)(tf * 16 + q * 4 + r) * 128] = C[tf][r] + other[r];
        }
    }
}

// ---------------------------------------------------------------------------
extern "C" void kernel_launch(void* const* d_in, const int* in_sizes, int n_in,
                              void* d_out, int out_size, void* d_ws, size_t ws_size,
                              hipStream_t stream)
{
    const float* x    = (const float*)d_in[0];   // (4,4096,128)
    const float* keys = (const float*)d_in[1];   // (64,128)
    const float* ops  = (const float*)d_in[2];   // (64,128,128)
    const float* Wq   = (const float*)d_in[3];   // (128,128)
    const float* bq   = (const float*)d_in[4];   // (128,)
    float* out = (float*)d_out;

    char* ws = (char*)d_ws;
    uint4v*   ops_sw = (uint4v*)ws;                        // 2 MB
    ushort_t* kp_sw  = (ushort_t*)(ws + 2097152);          // 16 KB
    float*    cb     = (float*)(ws + 2097152 + 16384);     // 256 B

    prep_kernel<<<576, 256, 0, stream>>>(ops, keys, Wq, bq, ops_sw, kp_sw, cb);
    main_kernel<<<256, 512, 0, stream>>>(x, cb, kp_sw, ops_sw, out);
}